// Round 1
// baseline (273.949 us; speedup 1.0000x reference)
//
#include <hip/hip_runtime.h>
#include <cfloat>
#include <math.h>

// ---------------- problem constants ----------------
#define NE   512            // num embeddings (K)
#define ED   64             // embedding dim (D)
#define NROW 131072         // 32*64*64 flattened NHWC rows
#define ROWS_TILE 64
#define NBLOCKS 256
#define TILES_PER_BLOCK (NROW / (ROWS_TILE * NBLOCKS))  // 8
#define ESTR 516            // padded LDS stride for eT (breaks staging bank conflicts)

// output layout (flat concat, all float32)
#define O_LOSS 0
#define O_Q    1ull                         // 8388608 elements, NCHW
#define O_PERP 8388609ull
#define O_DIST 8388610ull                   // 131072 x 512
#define O_IDX  75497474ull                  // 131072
#define O_ENC  75628546ull                  // 131072 x 512

#define SMEM_BYTES ((64*ESTR + 64*64 + 512 + 64 + 64) * 4)   // 151040 B

// ws layout: [0,2048) uint hist[512]; [2048,2056) double loss_sum; [2064,...) float sume2[512]

// ---------------- prep: zero accumulators, compute ||e_k||^2 (numpy pairwise order) ----
__global__ void vq_prep(const float* __restrict__ emb, unsigned int* __restrict__ hist,
                        double* __restrict__ lsum, float* __restrict__ sume2) {
    int k = threadIdx.x;   // 512 threads
    hist[k] = 0u;
    if (k == 0) *lsum = 0.0;
    float x[64];
    const float4* e4 = (const float4*)(emb + k * 64);
#pragma unroll
    for (int i = 0; i < 16; ++i) {
        float4 v = e4[i];
        x[4*i+0] = v.x; x[4*i+1] = v.y; x[4*i+2] = v.z; x[4*i+3] = v.w;
    }
    // numpy pairwise_sum for n=64: 8 accumulators then ((r0+r1)+(r2+r3))+((r4+r5)+(r6+r7))
    float r[8];
#pragma unroll
    for (int j = 0; j < 8; ++j) r[j] = x[j] * x[j];
#pragma unroll
    for (int i = 8; i < 64; i += 8)
#pragma unroll
        for (int j = 0; j < 8; ++j) r[j] += x[i+j] * x[i+j];
    sume2[k] = ((r[0]+r[1])+(r[2]+r[3])) + ((r[4]+r[5])+(r[6]+r[7]));
}

// ---------------- main kernel ----------------
__global__ __launch_bounds__(512, 1)
void vq_main(const float* __restrict__ in, const float* __restrict__ emb,
             float* __restrict__ out, unsigned int* __restrict__ hist,
             double* __restrict__ lsum, const float* __restrict__ sume2g) {
    extern __shared__ float smem[];
    float* eT      = smem;                  // [64][ESTR]
    float* xT      = eT + 64 * ESTR;        // [64][64]
    float* s_sume2 = xT + 64 * 64;          // [512]
    float* s_sumx2 = s_sume2 + 512;         // [64]
    int*   s_idx   = (int*)(s_sumx2 + 64);  // [64]

    const int tid = threadIdx.x;
    const int tk  = tid & 31;               // k-thread   (32)
    const int tr  = tid >> 5;               // row-thread (16), rows 4*tr..4*tr+3

    // ---- stage codebook transposed: eT[d][k] = emb[k*64+d]
    for (int it = 0; it < 16; ++it) {
        int idx4 = tid + 512 * it;          // 0..8191, one float4 of emb each
        int k  = idx4 >> 4;
        int dq = (idx4 & 15) << 2;
        float4 v = *(const float4*)(emb + k * 64 + dq);
        eT[(dq+0)*ESTR + k] = v.x;
        eT[(dq+1)*ESTR + k] = v.y;
        eT[(dq+2)*ESTR + k] = v.z;
        eT[(dq+3)*ESTR + k] = v.w;
    }
    s_sume2[tid] = sume2g[tid];

    double lacc = 0.0;

    for (int t = 0; t < TILES_PER_BLOCK; ++t) {
        const int row0 = (blockIdx.x * TILES_PER_BLOCK + t) * ROWS_TILE;
        const int n    = row0 >> 12;        // 4096 rows per image; tiles never cross images
        const int hw0  = row0 & 4095;
        const float* inbase = in + (size_t)(n * 64) * 4096 + hw0;

        __syncthreads();                    // protect xT/s_idx reuse from previous tile
        // ---- stage x tile transposed: xT[c][r] = in[n][c][hw0+r]  (coalesced)
#pragma unroll
        for (int it = 0; it < 8; ++it) {
            int idx = tid + 512 * it;       // 0..4095
            int c = idx >> 6, r = idx & 63;
            xT[c * 64 + r] = inbase[(size_t)c * 4096 + r];
        }
        __syncthreads();

        // ---- sum(x^2) per row, numpy pairwise order (first 64 threads)
        if (tid < 64) {
            float r8[8];
#pragma unroll
            for (int j = 0; j < 8; ++j) { float v = xT[j*64 + tid]; r8[j] = v * v; }
#pragma unroll
            for (int i = 8; i < 64; i += 8)
#pragma unroll
                for (int j = 0; j < 8; ++j) { float v = xT[(i+j)*64 + tid]; r8[j] += v * v; }
            s_sumx2[tid] = ((r8[0]+r8[1])+(r8[2]+r8[3])) + ((r8[4]+r8[5])+(r8[6]+r8[7]));
        }

        // ---- GEMM: 4 rows x 16 k per thread; k = 128*j + 4*tk + q
        float accf[4][16];
#pragma unroll
        for (int m = 0; m < 4; ++m)
#pragma unroll
            for (int kk = 0; kk < 16; ++kk) accf[m][kk] = 0.0f;

#pragma unroll 4
        for (int d = 0; d < 64; ++d) {
            float xv[4], ev[16];
            float4 tx = *(const float4*)&xT[d * 64 + 4 * tr];
            xv[0] = tx.x; xv[1] = tx.y; xv[2] = tx.z; xv[3] = tx.w;
#pragma unroll
            for (int j = 0; j < 4; ++j) {
                float4 te = *(const float4*)&eT[d * ESTR + 128 * j + 4 * tk];
                ev[4*j+0] = te.x; ev[4*j+1] = te.y; ev[4*j+2] = te.z; ev[4*j+3] = te.w;
            }
#pragma unroll
            for (int m = 0; m < 4; ++m)
#pragma unroll
                for (int kk = 0; kk < 16; ++kk)
                    accf[m][kk] = fmaf(xv[m], ev[kk], accf[m][kk]);
        }
        __syncthreads();                    // s_sumx2 ready

        // ---- distances, argmin, writes
        float sx[4];
#pragma unroll
        for (int m = 0; m < 4; ++m) sx[m] = s_sumx2[4 * tr + m];

        float bd[4]; int bk[4];
#pragma unroll
        for (int m = 0; m < 4; ++m) { bd[m] = FLT_MAX; bk[m] = 0; }

#pragma unroll
        for (int m = 0; m < 4; ++m) {
            const int row = row0 + 4 * tr + m;
            float* dout = out + O_DIST + (size_t)row * 512;
#pragma unroll
            for (int j = 0; j < 4; ++j) {
                float dv[4];
#pragma unroll
                for (int q = 0; q < 4; ++q) {
                    int k = 128 * j + 4 * tk + q;
                    float ts = sx[m] + s_sume2[k];            // fl(a+b)  (matches np broadcast add)
                    float dist = ts - 2.0f * accf[m][4*j+q];  // fl(t - 2m)
                    dv[q] = dist;
                    if (dist < bd[m]) { bd[m] = dist; bk[m] = k; }  // first-min tie-break (k ascending)
                }
                *(float4*)&dout[128 * j + 4 * tk] = make_float4(dv[0], dv[1], dv[2], dv[3]);
            }
        }

        // half-wave (32 lanes share tr) lexicographic argmin reduce
#pragma unroll
        for (int m = 0; m < 4; ++m) {
            float d0 = bd[m]; int k0 = bk[m];
            for (int s = 16; s >= 1; s >>= 1) {
                float od = __shfl_xor(d0, s, 64);
                int   ok = __shfl_xor(k0, s, 64);
                if (od < d0 || (od == d0 && ok < k0)) { d0 = od; k0 = ok; }
            }
            bk[m] = k0;
        }

#pragma unroll
        for (int m = 0; m < 4; ++m) {
            const int row = row0 + 4 * tr + m;
            const int kbest = bk[m];
            if (tk == 0) {
                out[O_IDX + row] = (float)kbest;
                s_idx[4 * tr + m] = kbest;
                atomicAdd(&hist[kbest], 1u);
            }
            float* eout = out + O_ENC + (size_t)row * 512;
#pragma unroll
            for (int j = 0; j < 4; ++j) {
                float ev[4];
#pragma unroll
                for (int q = 0; q < 4; ++q)
                    ev[q] = (128 * j + 4 * tk + q == kbest) ? 1.0f : 0.0f;
                *(float4*)&eout[128 * j + 4 * tk] = make_float4(ev[0], ev[1], ev[2], ev[3]);
            }
        }
        __syncthreads();                    // s_idx ready

        // ---- quantized (straight-through, NCHW) + loss partial
#pragma unroll
        for (int it = 0; it < 8; ++it) {
            int idx = tid + 512 * it;       // 0..4095
            int c = idx >> 6, r = idx & 63;
            float x = xT[c * 64 + r];
            float q = eT[c * ESTR + s_idx[r]];
            float dlt = q - x;              // fl(q-x), as reference
            lacc += (double)(dlt * dlt);
            out[O_Q + (size_t)(n * 64 + c) * 4096 + hw0 + r] = x + dlt;  // x + (q-x)
        }
    }

    // ---- loss reduction: wave reduce then one atomic per wave
    double v = lacc;
    for (int s = 32; s >= 1; s >>= 1) v += __shfl_down(v, s, 64);
    if ((tid & 63) == 0) atomicAdd(lsum, v);
}

// ---------------- final: perplexity + loss scalars ----------------
__global__ void vq_final(const unsigned int* __restrict__ hist,
                         const double* __restrict__ lsum, float* __restrict__ out) {
    __shared__ double part[8];
    int k = threadIdx.x;                    // 512 threads
    float p = (float)hist[k] / 131072.0f;   // exact (count * 2^-17)
    double v = (double)(p * logf(p + 1e-10f));
    for (int s = 32; s >= 1; s >>= 1) v += __shfl_down(v, s, 64);
    if ((k & 63) == 0) part[k >> 6] = v;
    __syncthreads();
    if (k == 0) {
        double S = 0.0;
#pragma unroll
        for (int i = 0; i < 8; ++i) S += part[i];
        out[O_PERP] = (float)exp(-S);
        float vl = (float)(*lsum / 8388608.0);
        out[O_LOSS] = vl + 0.25f * vl;      // q_latent + 0.25 * e_latent (equal values)
    }
}

// ---------------- launcher ----------------
extern "C" void kernel_launch(void* const* d_in, const int* in_sizes, int n_in,
                              void* d_out, int out_size, void* d_ws, size_t ws_size,
                              hipStream_t stream) {
    const float* in  = (const float*)d_in[0];   // (32,64,64,64) NCHW fp32
    const float* emb = (const float*)d_in[1];   // (512,64) fp32
    float* out = (float*)d_out;

    unsigned int* hist = (unsigned int*)d_ws;                    // 512 * 4 B
    double* lsum = (double*)((char*)d_ws + 2048);                // 8 B
    float* sume2 = (float*)((char*)d_ws + 2064);                 // 512 * 4 B

    hipFuncSetAttribute((const void*)vq_main,
                        hipFuncAttributeMaxDynamicSharedMemorySize, SMEM_BYTES);

    vq_prep<<<1, 512, 0, stream>>>(emb, hist, lsum, sume2);
    vq_main<<<NBLOCKS, 512, SMEM_BYTES, stream>>>(in, emb, out, hist, lsum, sume2);
    vq_final<<<1, 512, 0, stream>>>(hist, lsum, out);
}

// Round 2
// 212.202 us; speedup vs baseline: 1.2910x; 1.2910x over previous
//
#include <hip/hip_runtime.h>
#include <cfloat>
#include <math.h>

// ---------------- problem constants ----------------
#define NE   512            // num embeddings (K)
#define ED   64             // embedding dim (D)
#define NROW 131072         // 32*64*64 flattened NHWC rows
#define ROWS_TILE 64
#define NBLOCKS 256
#define TILES_PER_BLOCK (NROW / (ROWS_TILE * NBLOCKS))  // 8
#define ESTR 516            // padded LDS stride for eT (breaks staging bank conflicts)

// output layout (flat concat, all float32)
#define O_LOSS 0
#define O_Q    1ull                         // 8388608 elements, NCHW
#define O_PERP 8388609ull
#define O_DIST 8388610ull                   // 131072 x 512
#define O_IDX  75497474ull                  // 131072
#define O_ENC  75628546ull                  // 131072 x 512

#define SMEM_BYTES ((64*ESTR + 64*64 + 512 + 64 + 64) * 4)   // 151040 B

// ws layout: [0,2048) uint hist[512]; [2048,2056) double loss_sum; [2064,...) float sume2[512]

// LDS-only barrier: does NOT drain vmcnt, so fire-and-forget global stores
// from the previous tile keep flowing underneath the next tile's GEMM.
__device__ __forceinline__ void bar_lgkm() {
    asm volatile("s_waitcnt lgkmcnt(0)\n\ts_barrier" ::: "memory");
}

// ---------------- prep: zero accumulators, compute ||e_k||^2 (numpy pairwise order) ----
__global__ void vq_prep(const float* __restrict__ emb, unsigned int* __restrict__ hist,
                        double* __restrict__ lsum, float* __restrict__ sume2) {
    int k = threadIdx.x;   // 512 threads
    hist[k] = 0u;
    if (k == 0) *lsum = 0.0;
    float x[64];
    const float4* e4 = (const float4*)(emb + k * 64);
#pragma unroll
    for (int i = 0; i < 16; ++i) {
        float4 v = e4[i];
        x[4*i+0] = v.x; x[4*i+1] = v.y; x[4*i+2] = v.z; x[4*i+3] = v.w;
    }
    // numpy pairwise_sum for n=64: 8 accumulators then ((r0+r1)+(r2+r3))+((r4+r5)+(r6+r7))
    float r[8];
#pragma unroll
    for (int j = 0; j < 8; ++j) r[j] = x[j] * x[j];
#pragma unroll
    for (int i = 8; i < 64; i += 8)
#pragma unroll
        for (int j = 0; j < 8; ++j) r[j] += x[i+j] * x[i+j];
    sume2[k] = ((r[0]+r[1])+(r[2]+r[3])) + ((r[4]+r[5])+(r[6]+r[7]));
}

// ---------------- main kernel ----------------
__global__ __launch_bounds__(512, 1)
void vq_main(const float* __restrict__ in, const float* __restrict__ emb,
             float* __restrict__ out, unsigned int* __restrict__ hist,
             double* __restrict__ lsum, const float* __restrict__ sume2g) {
    extern __shared__ float smem[];
    float* eT      = smem;                  // [64][ESTR]
    float* xT      = eT + 64 * ESTR;        // [64][64]
    float* s_sume2 = xT + 64 * 64;          // [512]
    float* s_sumx2 = s_sume2 + 512;         // [64]
    int*   s_idx   = (int*)(s_sumx2 + 64);  // [64]

    const int tid = threadIdx.x;
    const int tk  = tid & 63;               // k-thread (64): k = 256*j + 4*tk + q
    const int tr  = tid >> 6;               // wave id (8): rows 8*tr .. 8*tr+7

    // ---- stage codebook transposed: eT[d][k] = emb[k*64+d]
    for (int it = 0; it < 16; ++it) {
        int idx4 = tid + 512 * it;          // 0..8191, one float4 of emb each
        int k  = idx4 >> 4;
        int dq = (idx4 & 15) << 2;
        float4 v = *(const float4*)(emb + k * 64 + dq);
        eT[(dq+0)*ESTR + k] = v.x;
        eT[(dq+1)*ESTR + k] = v.y;
        eT[(dq+2)*ESTR + k] = v.z;
        eT[(dq+3)*ESTR + k] = v.w;
    }
    s_sume2[tid] = sume2g[tid];

    // ---- stage first x tile: xT[c][r] = in[n][c][hw0+r]
    {
        const int row0 = blockIdx.x * TILES_PER_BLOCK * ROWS_TILE;
        const int n    = row0 >> 12;
        const int hw0  = row0 & 4095;
        const float* inbase = in + (size_t)(n * 64) * 4096 + hw0;
#pragma unroll
        for (int it = 0; it < 2; ++it) {
            int idx4 = tid + 512 * it;      // 0..1023 float4s
            int c = idx4 >> 4, qd = (idx4 & 15) << 2;
            float4 v = *(const float4*)(inbase + (size_t)c * 4096 + qd);
            *(float4*)&xT[c * 64 + qd] = v;
        }
    }
    bar_lgkm();

    double lacc = 0.0;

    for (int t = 0; t < TILES_PER_BLOCK; ++t) {
        const int row0 = (blockIdx.x * TILES_PER_BLOCK + t) * ROWS_TILE;
        const int n    = row0 >> 12;        // 4096 rows per image; tiles never cross images
        const int hw0  = row0 & 4095;

        // ---- sum(x^2) per row, numpy pairwise order (first 64 threads)
        if (tid < 64) {
            float r8[8];
#pragma unroll
            for (int j = 0; j < 8; ++j) { float v = xT[j*64 + tid]; r8[j] = v * v; }
#pragma unroll
            for (int i = 8; i < 64; i += 8)
#pragma unroll
                for (int j = 0; j < 8; ++j) { float v = xT[(i+j)*64 + tid]; r8[j] += v * v; }
            s_sumx2[tid] = ((r8[0]+r8[1])+(r8[2]+r8[3])) + ((r8[4]+r8[5])+(r8[6]+r8[7]));
        }

        // ---- GEMM: 8 rows x 8 k per thread (4 LDS b128 per 64 FMA)
        float accf[8][8];
#pragma unroll
        for (int m = 0; m < 8; ++m)
#pragma unroll
            for (int kk = 0; kk < 8; ++kk) accf[m][kk] = 0.0f;

#pragma unroll 4
        for (int d = 0; d < 64; ++d) {
            float4 x0 = *(const float4*)&xT[d * 64 + 8 * tr];       // wave-uniform (broadcast)
            float4 x1 = *(const float4*)&xT[d * 64 + 8 * tr + 4];
            float4 e0 = *(const float4*)&eT[d * ESTR + 4 * tk];     // contiguous 1KB/wave
            float4 e1 = *(const float4*)&eT[d * ESTR + 256 + 4 * tk];
            float xv[8] = {x0.x, x0.y, x0.z, x0.w, x1.x, x1.y, x1.z, x1.w};
            float ev[8] = {e0.x, e0.y, e0.z, e0.w, e1.x, e1.y, e1.z, e1.w};
#pragma unroll
            for (int m = 0; m < 8; ++m)
#pragma unroll
                for (int kk = 0; kk < 8; ++kk)
                    accf[m][kk] = fmaf(xv[m], ev[kk], accf[m][kk]);
        }
        bar_lgkm();                          // s_sumx2 visible to all waves

        // ---- prefetch next x tile into registers BEFORE issuing this tile's stores
        // (vmcnt retires in issue order: loads-before-stores means the ds_write's
        //  vmcnt wait does NOT drain the store queue)
        float4 pf[2];
        if (t + 1 < TILES_PER_BLOCK) {
            const int row0n = row0 + ROWS_TILE;
            const int nn    = row0n >> 12;
            const int hw0n  = row0n & 4095;
            const float* inbase = in + (size_t)(nn * 64) * 4096 + hw0n;
#pragma unroll
            for (int it = 0; it < 2; ++it) {
                int idx4 = tid + 512 * it;
                int c = idx4 >> 4, qd = (idx4 & 15) << 2;
                pf[it] = *(const float4*)(inbase + (size_t)c * 4096 + qd);
            }
            __builtin_amdgcn_sched_barrier(0);  // pin loads before the store phase
        }

        // ---- distances, argmin, writes
        float4 sxa = *(const float4*)&s_sumx2[8 * tr];      // wave-uniform
        float4 sxb = *(const float4*)&s_sumx2[8 * tr + 4];
        float sx[8] = {sxa.x, sxa.y, sxa.z, sxa.w, sxb.x, sxb.y, sxb.z, sxb.w};
        float4 seA = *(const float4*)&s_sume2[4 * tk];      // this thread's 8 ||e||^2
        float4 seB = *(const float4*)&s_sume2[256 + 4 * tk];
        float se[8] = {seA.x, seA.y, seA.z, seA.w, seB.x, seB.y, seB.z, seB.w};

        int bk[8];
#pragma unroll
        for (int m = 0; m < 8; ++m) {
            const int row = row0 + 8 * tr + m;
            float* dout = out + O_DIST + (size_t)row * 512;
            float bd = FLT_MAX; int bki = 0;
#pragma unroll
            for (int j = 0; j < 2; ++j) {
                float dv[4];
#pragma unroll
                for (int q = 0; q < 4; ++q) {
                    int k = 256 * j + 4 * tk + q;
                    float ts = sx[m] + se[4*j+q];             // fl(a+b)  (matches np broadcast add)
                    float dist = ts - 2.0f * accf[m][4*j+q];  // fl(t - 2m)
                    dv[q] = dist;
                    if (dist < bd) { bd = dist; bki = k; }    // first-min tie-break (k ascending)
                }
                *(float4*)&dout[256 * j + 4 * tk] = make_float4(dv[0], dv[1], dv[2], dv[3]);
            }
            // full-wave lexicographic argmin reduce (row is wave-private)
            for (int s = 32; s >= 1; s >>= 1) {
                float od = __shfl_xor(bd, s, 64);
                int   ok = __shfl_xor(bki, s, 64);
                if (od < bd || (od == bd && ok < bki)) { bd = od; bki = ok; }
            }
            bk[m] = bki;
        }

#pragma unroll
        for (int m = 0; m < 8; ++m) {
            const int row = row0 + 8 * tr + m;
            const int kbest = bk[m];
            if (tk == 0) {
                out[O_IDX + row] = (float)kbest;
                s_idx[8 * tr + m] = kbest;
                atomicAdd(&hist[kbest], 1u);
            }
            float* eout = out + O_ENC + (size_t)row * 512;
#pragma unroll
            for (int j = 0; j < 2; ++j) {
                float ev[4];
#pragma unroll
                for (int q = 0; q < 4; ++q)
                    ev[q] = (256 * j + 4 * tk + q == kbest) ? 1.0f : 0.0f;
                *(float4*)&eout[256 * j + 4 * tk] = make_float4(ev[0], ev[1], ev[2], ev[3]);
            }
        }
        bar_lgkm();                          // s_idx visible

        // ---- quantized (straight-through, NCHW) + loss partial
#pragma unroll
        for (int it = 0; it < 8; ++it) {
            int idx = tid + 512 * it;       // 0..4095
            int c = idx >> 6, r = idx & 63;
            float x = xT[c * 64 + r];
            float q = eT[c * ESTR + s_idx[r]];
            float dlt = q - x;              // fl(q-x), as reference
            lacc += (double)(dlt * dlt);
            out[O_Q + (size_t)(n * 64 + c) * 4096 + hw0 + r] = x + dlt;  // x + (q-x)
        }

        // ---- commit prefetched x tile to LDS for next iteration
        if (t + 1 < TILES_PER_BLOCK) {
            bar_lgkm();                      // all xT(t) readers done
#pragma unroll
            for (int it = 0; it < 2; ++it) {
                int idx4 = tid + 512 * it;
                int c = idx4 >> 4, qd = (idx4 & 15) << 2;
                *(float4*)&xT[c * 64 + qd] = pf[it];
            }
            bar_lgkm();                      // xT(t+1) visible
        }
    }

    // ---- loss reduction: wave reduce then one atomic per wave
    double v = lacc;
    for (int s = 32; s >= 1; s >>= 1) v += __shfl_down(v, s, 64);
    if ((tid & 63) == 0) atomicAdd(lsum, v);
}

// ---------------- final: perplexity + loss scalars ----------------
__global__ void vq_final(const unsigned int* __restrict__ hist,
                         const double* __restrict__ lsum, float* __restrict__ out) {
    __shared__ double part[8];
    int k = threadIdx.x;                    // 512 threads
    float p = (float)hist[k] / 131072.0f;   // exact (count * 2^-17)
    double v = (double)(p * logf(p + 1e-10f));
    for (int s = 32; s >= 1; s >>= 1) v += __shfl_down(v, s, 64);
    if ((k & 63) == 0) part[k >> 6] = v;
    __syncthreads();
    if (k == 0) {
        double S = 0.0;
#pragma unroll
        for (int i = 0; i < 8; ++i) S += part[i];
        out[O_PERP] = (float)exp(-S);
        float vl = (float)(*lsum / 8388608.0);
        out[O_LOSS] = vl + 0.25f * vl;      // q_latent + 0.25 * e_latent (equal values)
    }
}

// ---------------- launcher ----------------
extern "C" void kernel_launch(void* const* d_in, const int* in_sizes, int n_in,
                              void* d_out, int out_size, void* d_ws, size_t ws_size,
                              hipStream_t stream) {
    const float* in  = (const float*)d_in[0];   // (32,64,64,64) NCHW fp32
    const float* emb = (const float*)d_in[1];   // (512,64) fp32
    float* out = (float*)d_out;

    unsigned int* hist = (unsigned int*)d_ws;                    // 512 * 4 B
    double* lsum = (double*)((char*)d_ws + 2048);                // 8 B
    float* sume2 = (float*)((char*)d_ws + 2064);                 // 512 * 4 B

    hipFuncSetAttribute((const void*)vq_main,
                        hipFuncAttributeMaxDynamicSharedMemorySize, SMEM_BYTES);

    vq_prep<<<1, 512, 0, stream>>>(emb, hist, lsum, sume2);
    vq_main<<<NBLOCKS, 512, SMEM_BYTES, stream>>>(in, emb, out, hist, lsum, sume2);
    vq_final<<<1, 512, 0, stream>>>(hist, lsum, out);
}